// Round 3
// baseline (92.880 us; speedup 1.0000x reference)
//
#include <hip/hip_runtime.h>
#include <hip/hip_bf16.h>

// Fused KV-cache append + causal SDPA, flash-attention style, bf16 MFMA.
// B=4 S=128 H=32 D=128 T=2048, start read from input (1024).
// (Round-2 resubmit: rounds 0-1 died on container infra, no kernel signal.)

typedef short bf16x8 __attribute__((ext_vector_type(8)));
typedef float f32x4  __attribute__((ext_vector_type(4)));

constexpr int B = 4, S = 128, H = 32, D = 128, T = 2048;
constexpr int QBLK = 64, KVBLK = 64;
constexpr int NW = 4;                       // waves per block
constexpr int KP = D + 8;                   // K_lds padded row (bf16 elems)
constexpr int VP = KVBLK + 8;               // Vt_lds padded row
constexpr int PP = KVBLK + 8;               // P_lds padded row
constexpr float SCALE = 0.08838834764831845f;  // 1/sqrt(128)

__device__ __forceinline__ short f2bf(float f) {
    union { float f; unsigned u; } c{f};
    unsigned r = (c.u + 0x7fffu + ((c.u >> 16) & 1u)) >> 16;
    return (short)r;
}

__global__ __launch_bounds__(256, 1) void sdpa_fused_kernel(
    const float* __restrict__ qg, const float* __restrict__ kin,
    const float* __restrict__ vin, const float* __restrict__ kc,
    const float* __restrict__ vc, const int* __restrict__ ip,
    float* __restrict__ out)
{
    __shared__ short K_lds[KVBLK][KP];     // [kv][d]  bf16
    __shared__ short Vt_lds[D][VP];        // [d][kv]  bf16 (transposed)
    __shared__ short P_lds[NW][16][PP];    // per-wave P tile

    const int start = ip[0];
    const int bh = blockIdx.x;
    const int b  = bh >> 5;                // H = 32
    const int h  = bh & 31;
    const int q0 = blockIdx.y * QBLK;
    const int t  = threadIdx.x;
    const int w  = t >> 6;
    const int l  = t & 63;
    const int l16 = l & 15;
    const int lg  = l >> 4;                // 0..3

    // ---- Q fragments: wave owns rows q0+16w .. q0+16w+15 ----
    const int qrow = q0 + w * 16 + l16;
    const float* qp = qg + (((size_t)b * S + qrow) * H + h) * D;
    bf16x8 qfrag[4];
    #pragma unroll
    for (int ks = 0; ks < 4; ++ks) {
        const float* p = qp + ks * 32 + lg * 8;
        #pragma unroll
        for (int i = 0; i < 8; ++i) qfrag[ks][i] = f2bf(p[i]);
    }

    f32x4 oacc[8];
    #pragma unroll
    for (int n = 0; n < 8; ++n) oacc[n] = {0.f, 0.f, 0.f, 0.f};
    float m[4], ssum[4];
    #pragma unroll
    for (int j = 0; j < 4; ++j) { m[j] = -INFINITY; ssum[j] = 0.f; }

    const int kv_end  = start + q0 + QBLK;              // exclusive
    const int ntiles  = (kv_end + KVBLK - 1) / KVBLK;

    for (int tile = 0; tile < ntiles; ++tile) {
        const int j0 = tile * KVBLK;

        // ---- stage K (row-major) and V (transposed) into LDS as bf16 ----
        {
            const int r8 = t >> 5;         // 0..7
            const int c  = t & 31;         // 0..31 (float4 chunk)
            #pragma unroll
            for (int p = 0; p < 8; ++p) {
                const int r = p * 8 + r8;
                const int j = j0 + r;
                const float *ksrc, *vsrc;
                if (j < start) {
                    size_t off = (((size_t)b * T + j) * H + h) * (size_t)D;
                    ksrc = kc + off; vsrc = vc + off;
                } else {
                    size_t off = (((size_t)b * S + (j - start)) * H + h) * (size_t)D;
                    ksrc = kin + off; vsrc = vin + off;
                }
                float4 k4 = ((const float4*)ksrc)[c];
                float4 v4 = ((const float4*)vsrc)[c];
                short4 k4b = { f2bf(k4.x), f2bf(k4.y), f2bf(k4.z), f2bf(k4.w) };
                *(short4*)&K_lds[r][c * 4] = k4b;
                Vt_lds[c * 4 + 0][r] = f2bf(v4.x);
                Vt_lds[c * 4 + 1][r] = f2bf(v4.y);
                Vt_lds[c * 4 + 2][r] = f2bf(v4.z);
                Vt_lds[c * 4 + 3][r] = f2bf(v4.w);
            }
        }
        __syncthreads();

        // ---- QK^T: 4 N-subtiles of 16 kv cols, K-dim = 128 = 4 steps ----
        f32x4 sacc[4];
        #pragma unroll
        for (int n = 0; n < 4; ++n) sacc[n] = {0.f, 0.f, 0.f, 0.f};
        #pragma unroll
        for (int n = 0; n < 4; ++n) {
            #pragma unroll
            for (int ks = 0; ks < 4; ++ks) {
                bf16x8 bfrag = *(const bf16x8*)&K_lds[n * 16 + l16][ks * 32 + lg * 8];
                sacc[n] = __builtin_amdgcn_mfma_f32_16x16x32_bf16(
                    qfrag[ks], bfrag, sacc[n], 0, 0, 0);
            }
        }

        // ---- scale + causal mask + online softmax ----
        float sv[4][4];                    // [row-reg][n]
        float pmax[4];
        #pragma unroll
        for (int j = 0; j < 4; ++j) pmax[j] = -INFINITY;
        #pragma unroll
        for (int n = 0; n < 4; ++n) {
            const int kvj = j0 + n * 16 + l16;
            #pragma unroll
            for (int j = 0; j < 4; ++j) {
                const int qi = q0 + w * 16 + lg * 4 + j;
                float s = sacc[n][j] * SCALE;
                if (kvj > start + qi) s = -INFINITY;
                sv[j][n] = s;
                pmax[j] = fmaxf(pmax[j], s);
            }
        }
        #pragma unroll
        for (int j = 0; j < 4; ++j) {      // row max across the 16-lane group
            float v = pmax[j];
            v = fmaxf(v, __shfl_xor(v, 1));
            v = fmaxf(v, __shfl_xor(v, 2));
            v = fmaxf(v, __shfl_xor(v, 4));
            v = fmaxf(v, __shfl_xor(v, 8));
            pmax[j] = v;
        }
        float corr[4];
        #pragma unroll
        for (int j = 0; j < 4; ++j) {
            float mnew = fmaxf(m[j], pmax[j]);
            corr[j] = __expf(m[j] - mnew);     // first tile: exp(-inf)=0
            m[j] = mnew;
        }
        float tsum[4] = {0.f, 0.f, 0.f, 0.f};
        short pbf[4][4];
        #pragma unroll
        for (int n = 0; n < 4; ++n) {
            #pragma unroll
            for (int j = 0; j < 4; ++j) {
                float p = __expf(sv[j][n] - m[j]);   // masked -> exp(-inf)=0
                tsum[j] += p;
                pbf[j][n] = f2bf(p);
            }
        }
        #pragma unroll
        for (int j = 0; j < 4; ++j) {      // row sum across the 16-lane group
            float v = tsum[j];
            v += __shfl_xor(v, 1);
            v += __shfl_xor(v, 2);
            v += __shfl_xor(v, 4);
            v += __shfl_xor(v, 8);
            ssum[j] = ssum[j] * corr[j] + v;
        }
        #pragma unroll
        for (int n = 0; n < 8; ++n) {
            #pragma unroll
            for (int j = 0; j < 4; ++j) oacc[n][j] *= corr[j];
        }

        // ---- P (D-layout) -> LDS -> A-layout fragments ----
        #pragma unroll
        for (int n = 0; n < 4; ++n) {
            #pragma unroll
            for (int j = 0; j < 4; ++j)
                P_lds[w][lg * 4 + j][n * 16 + l16] = pbf[j][n];
        }
        asm volatile("s_waitcnt lgkmcnt(0)" ::: "memory");
        __builtin_amdgcn_sched_barrier(0);

        // ---- PV: out(16x128) += P(16x64) x V(64x128) ----
        #pragma unroll
        for (int ks = 0; ks < 2; ++ks) {
            bf16x8 afrag = *(const bf16x8*)&P_lds[w][l16][ks * 32 + lg * 8];
            #pragma unroll
            for (int n = 0; n < 8; ++n) {
                bf16x8 bfrag = *(const bf16x8*)&Vt_lds[n * 16 + l16][ks * 32 + lg * 8];
                oacc[n] = __builtin_amdgcn_mfma_f32_16x16x32_bf16(
                    afrag, bfrag, oacc[n], 0, 0, 0);
            }
        }
        __syncthreads();
    }

    // ---- epilogue: divide by row sum, write [B, S, H*D] fp32 ----
    #pragma unroll
    for (int j = 0; j < 4; ++j) {
        const float inv = 1.0f / ssum[j];
        const int qi = q0 + w * 16 + lg * 4 + j;
        float* op = out + ((size_t)b * S + qi) * (size_t)(H * D) + h * D;
        #pragma unroll
        for (int n = 0; n < 8; ++n)
            op[n * 16 + l16] = oacc[n][j] * inv;
    }
}

extern "C" void kernel_launch(void* const* d_in, const int* in_sizes, int n_in,
                              void* d_out, int out_size, void* d_ws, size_t ws_size,
                              hipStream_t stream) {
    const float* q  = (const float*)d_in[0];
    const float* k  = (const float*)d_in[1];
    const float* v  = (const float*)d_in[2];
    const float* kc = (const float*)d_in[3];
    const float* vc = (const float*)d_in[4];
    const int*   ip = (const int*)d_in[5];
    float* out = (float*)d_out;

    dim3 grid(B * H, S / QBLK);
    dim3 block(256);
    sdpa_fused_kernel<<<grid, block, 0, stream>>>(q, k, v, kc, vc, ip, out);
}

// Round 4
// 64.962 us; speedup vs baseline: 1.4298x; 1.4298x over previous
//
#include <hip/hip_runtime.h>
#include <hip/hip_bf16.h>

// Fused KV-cache append + causal SDPA, flash-attention style, bf16 MFMA.
// B=4 S=128 H=32 D=128 T=2048, start read from input (1024).
// R4: (1) KV-split flash-decode NS=3 (768 blocks, 3/CU) + combine kernel,
//     (2) V staged via 4x4 register transpose into XOR-swizzled linear LDS
//         (kills the 1.96e7 bank-conflict scatter).

typedef short bf16x8 __attribute__((ext_vector_type(8)));
typedef float f32x4  __attribute__((ext_vector_type(4)));

constexpr int B = 4, S = 128, H = 32, D = 128, T = 2048;
constexpr int QBLK = 64, KVBLK = 64;
constexpr int NW = 4;                       // waves per block
constexpr int NS = 3;                       // KV chunks (3 blocks/CU exactly)
constexpr int KP = D + 8;                   // K_lds padded row (bf16 elems)
constexpr int PP = KVBLK + 8;               // P_lds padded row
constexpr float SCALE = 0.08838834764831845f;  // 1/sqrt(128)
constexpr float MNEG = -1e30f;              // sentinel (NaN-free vs -inf)

__device__ __forceinline__ short f2bf(float f) {
    union { float f; unsigned u; } c{f};
    unsigned r = (c.u + 0x7fffu + ((c.u >> 16) & 1u)) >> 16;
    return (short)r;
}

// MODE 0: single-pass, writes out directly (fallback if ws too small).
// MODE 1: KV-chunk partials (unnormalized O, m, l) to workspace.
template<int MODE>
__global__ __launch_bounds__(256, 1) void sdpa_kernel(
    const float* __restrict__ qg, const float* __restrict__ kin,
    const float* __restrict__ vin, const float* __restrict__ kc,
    const float* __restrict__ vc, const int* __restrict__ ip,
    float* __restrict__ out, float* __restrict__ wsO, float2* __restrict__ wsML)
{
    __shared__ short K_lds[KVBLK][KP];      // [kv][d]  bf16
    __shared__ short V_lds[D * KVBLK];      // [d][kv]  bf16, XOR-swizzled
    __shared__ short P_lds[NW][16][PP];     // per-wave P tile

    const int start = ip[0];
    const int bh = blockIdx.x;
    const int b  = bh >> 5;                 // H = 32
    const int h  = bh & 31;
    const int q0 = blockIdx.y * QBLK;
    const int z  = (MODE == 1) ? blockIdx.z : 0;
    const int t  = threadIdx.x;
    const int w  = t >> 6;
    const int l  = t & 63;
    const int l16 = l & 15;
    const int lg  = l >> 4;                 // 0..3

    // ---- Q fragments: wave owns rows q0+16w .. q0+16w+15 ----
    const int qrow = q0 + w * 16 + l16;
    const float* qp = qg + (((size_t)b * S + qrow) * H + h) * D;
    bf16x8 qfrag[4];
    #pragma unroll
    for (int ks = 0; ks < 4; ++ks) {
        const float* p = qp + ks * 32 + lg * 8;
        #pragma unroll
        for (int i = 0; i < 8; ++i) qfrag[ks][i] = f2bf(p[i]);
    }

    f32x4 oacc[8];
    #pragma unroll
    for (int n = 0; n < 8; ++n) oacc[n] = {0.f, 0.f, 0.f, 0.f};
    float m[4], ssum[4];
    #pragma unroll
    for (int j = 0; j < 4; ++j) { m[j] = MNEG; ssum[j] = 0.f; }

    const int kv_end = start + q0 + QBLK;               // exclusive, 64-aligned
    const int nt     = (kv_end + KVBLK - 1) / KVBLK;
    int t_lo = 0, t_hi = nt;
    if (MODE == 1) {
        const int ct = (nt + NS - 1) / NS;
        t_lo = z * ct;
        t_hi = min(t_lo + ct, nt);
    }

    for (int tile = t_lo; tile < t_hi; ++tile) {
        const int j0 = tile * KVBLK;

        // ---- stage K row-major: lanes = 2 rows x 32 float4 chunks ----
        {
            const int r8 = t >> 5;          // 0..7
            const int c  = t & 31;          // float4 chunk
            #pragma unroll
            for (int p = 0; p < 8; ++p) {
                const int r = p * 8 + r8;
                const int j = j0 + r;
                const float* ksrc = (j < start)
                    ? kc  + (((size_t)b * T + j) * H + h) * (size_t)D
                    : kin + (((size_t)b * S + (j - start)) * H + h) * (size_t)D;
                float4 k4 = ((const float4*)ksrc)[c];
                short4 k4b = { f2bf(k4.x), f2bf(k4.y), f2bf(k4.z), f2bf(k4.w) };
                *(short4*)&K_lds[r][c * 4] = k4b;
            }
        }
        // ---- stage V via 4x4 register transpose, swizzled short4 writes ----
        {
            const int rb  = t & 15;         // kv 4-row block
            const int cb0 = t >> 4;         // 0..15
            #pragma unroll
            for (int it = 0; it < 2; ++it) {
                const int cb = cb0 + 16 * it;   // float4 chunk (d block)
                float4 a[4];
                #pragma unroll
                for (int k = 0; k < 4; ++k) {
                    const int j = j0 + rb * 4 + k;
                    const float* vsrc = (j < start)
                        ? vc  + (((size_t)b * T + j) * H + h) * (size_t)D
                        : vin + (((size_t)b * S + (j - start)) * H + h) * (size_t)D;
                    a[k] = ((const float4*)vsrc)[cb];
                }
                #pragma unroll
                for (int jj = 0; jj < 4; ++jj) {
                    const int d = cb * 4 + jj;
                    short4 wv = { f2bf(((const float*)&a[0])[jj]),
                                  f2bf(((const float*)&a[1])[jj]),
                                  f2bf(((const float*)&a[2])[jj]),
                                  f2bf(((const float*)&a[3])[jj]) };
                    int off = d * (KVBLK * 2) + rb * 8;
                    off ^= (d & 7) << 4;
                    *(short4*)((char*)V_lds + off) = wv;
                }
            }
        }
        __syncthreads();

        // ---- QK^T: 4 N-subtiles of 16 kv cols, K-dim = 128 = 4 steps ----
        f32x4 sacc[4];
        #pragma unroll
        for (int n = 0; n < 4; ++n) sacc[n] = {0.f, 0.f, 0.f, 0.f};
        #pragma unroll
        for (int n = 0; n < 4; ++n) {
            #pragma unroll
            for (int ks = 0; ks < 4; ++ks) {
                bf16x8 bfrag = *(const bf16x8*)&K_lds[n * 16 + l16][ks * 32 + lg * 8];
                sacc[n] = __builtin_amdgcn_mfma_f32_16x16x32_bf16(
                    qfrag[ks], bfrag, sacc[n], 0, 0, 0);
            }
        }

        // ---- scale + causal mask + online softmax (sentinel MNEG) ----
        float sv[4][4];
        float pmax[4];
        #pragma unroll
        for (int j = 0; j < 4; ++j) pmax[j] = MNEG;
        #pragma unroll
        for (int n = 0; n < 4; ++n) {
            const int kvj = j0 + n * 16 + l16;
            #pragma unroll
            for (int j = 0; j < 4; ++j) {
                const int qi = q0 + w * 16 + lg * 4 + j;
                float s = sacc[n][j] * SCALE;
                if (kvj > start + qi) s = MNEG;
                sv[j][n] = s;
                pmax[j] = fmaxf(pmax[j], s);
            }
        }
        #pragma unroll
        for (int j = 0; j < 4; ++j) {       // row max across 16-lane group
            float v = pmax[j];
            v = fmaxf(v, __shfl_xor(v, 1));
            v = fmaxf(v, __shfl_xor(v, 2));
            v = fmaxf(v, __shfl_xor(v, 4));
            v = fmaxf(v, __shfl_xor(v, 8));
            pmax[j] = v;
        }
        float corr[4];
        #pragma unroll
        for (int j = 0; j < 4; ++j) {
            float mnew = fmaxf(m[j], pmax[j]);
            corr[j] = __expf(m[j] - mnew);  // MNEG-MNEG=0 -> 1, oacc=0: safe
            m[j] = mnew;
        }
        float tsum[4] = {0.f, 0.f, 0.f, 0.f};
        short pbf[4][4];
        #pragma unroll
        for (int n = 0; n < 4; ++n) {
            #pragma unroll
            for (int j = 0; j < 4; ++j) {
                float p = __expf(sv[j][n] - m[j]);
                tsum[j] += p;
                pbf[j][n] = f2bf(p);
            }
        }
        #pragma unroll
        for (int j = 0; j < 4; ++j) {       // row sum across 16-lane group
            float v = tsum[j];
            v += __shfl_xor(v, 1);
            v += __shfl_xor(v, 2);
            v += __shfl_xor(v, 4);
            v += __shfl_xor(v, 8);
            ssum[j] = ssum[j] * corr[j] + v;
        }
        #pragma unroll
        for (int n = 0; n < 8; ++n) {
            #pragma unroll
            for (int j = 0; j < 4; ++j) oacc[n][j] *= corr[j];
        }

        // ---- P (D-layout) -> LDS -> A-layout fragments ----
        #pragma unroll
        for (int n = 0; n < 4; ++n) {
            #pragma unroll
            for (int j = 0; j < 4; ++j)
                P_lds[w][lg * 4 + j][n * 16 + l16] = pbf[j][n];
        }
        asm volatile("s_waitcnt lgkmcnt(0)" ::: "memory");
        __builtin_amdgcn_sched_barrier(0);

        // ---- PV: out(16x128) += P(16x64) x V(64x128) ----
        #pragma unroll
        for (int ks = 0; ks < 2; ++ks) {
            bf16x8 afrag = *(const bf16x8*)&P_lds[w][l16][ks * 32 + lg * 8];
            #pragma unroll
            for (int n = 0; n < 8; ++n) {
                int off = (n * 16 + l16) * (KVBLK * 2) + ks * 64 + lg * 16;
                off ^= (l16 & 7) << 4;
                bf16x8 bfrag = *(const bf16x8*)((const char*)V_lds + off);
                oacc[n] = __builtin_amdgcn_mfma_f32_16x16x32_bf16(
                    afrag, bfrag, oacc[n], 0, 0, 0);
            }
        }
        __syncthreads();
    }

    // ---- epilogue ----
    #pragma unroll
    for (int j = 0; j < 4; ++j) {
        const int qi = q0 + w * 16 + lg * 4 + j;
        if (MODE == 0) {
            const float inv = 1.0f / ssum[j];
            float* op = out + ((size_t)b * S + qi) * (size_t)(H * D) + h * D;
            #pragma unroll
            for (int n = 0; n < 8; ++n)
                op[n * 16 + l16] = oacc[n][j] * inv;
        } else {
            float* op = wsO + ((((size_t)z * B + b) * S + qi) * H + h) * (size_t)D;
            #pragma unroll
            for (int n = 0; n < 8; ++n)
                op[n * 16 + l16] = oacc[n][j];
            if (l16 == 0)
                wsML[(((size_t)z * B + b) * S + qi) * H + h] = make_float2(m[j], ssum[j]);
        }
    }
}

__global__ __launch_bounds__(256) void combine_kernel(
    const float* __restrict__ wsO, const float2* __restrict__ wsML,
    float* __restrict__ out)
{
    constexpr int R = B * S * H;            // 16384 rows
    constexpr int TOT = R * D;
    for (int idx = blockIdx.x * 256 + threadIdx.x; idx < TOT;
         idx += gridDim.x * 256) {
        const int row = idx >> 7;           // D = 128
        float2 e[NS];
        float M = MNEG;
        #pragma unroll
        for (int c = 0; c < NS; ++c) {
            e[c] = wsML[(size_t)c * R + row];
            M = fmaxf(M, e[c].x);
        }
        float L = 0.f, val = 0.f;
        #pragma unroll
        for (int c = 0; c < NS; ++c) {
            const float wgt = __expf(e[c].x - M);
            L   += e[c].y * wgt;
            val += wsO[(size_t)c * TOT + idx] * wgt;
        }
        out[idx] = val / L;
    }
}

extern "C" void kernel_launch(void* const* d_in, const int* in_sizes, int n_in,
                              void* d_out, int out_size, void* d_ws, size_t ws_size,
                              hipStream_t stream) {
    const float* q  = (const float*)d_in[0];
    const float* k  = (const float*)d_in[1];
    const float* v  = (const float*)d_in[2];
    const float* kc = (const float*)d_in[3];
    const float* vc = (const float*)d_in[4];
    const int*   ip = (const int*)d_in[5];
    float* out = (float*)d_out;

    const size_t nO  = (size_t)NS * B * S * H * D;
    const size_t nML = (size_t)NS * B * S * H;          // float2 elements
    const size_t need = (nO + 2 * nML) * sizeof(float);

    if (ws_size >= need) {
        float*  wsO  = (float*)d_ws;
        float2* wsML = (float2*)(wsO + nO);
        sdpa_kernel<1><<<dim3(B * H, S / QBLK, NS), 256, 0, stream>>>(
            q, k, v, kc, vc, ip, out, wsO, wsML);
        combine_kernel<<<2048, 256, 0, stream>>>(wsO, wsML, out);
    } else {
        sdpa_kernel<0><<<dim3(B * H, S / QBLK), 256, 0, stream>>>(
            q, k, v, kc, vc, ip, out, nullptr, nullptr);
    }
}